// Round 3
// baseline (373.951 us; speedup 1.0000x reference)
//
#include <hip/hip_runtime.h>
#include <cstddef>
#include <cstdint>

// ST-GCN block, MFMA + software-pipelined staging.
// Stage 1 (swapped operands): Yt[pos=64][os=192] -> stored transposed as Ys[os][pos].
//   pos = m*32 + v (v padded 25->32, pad rows zeroed once).
// Stage 2: Z[o=64][w] = sum_s Y_s[o][v] PA_s[v][w], K=32 (PA pads zero).
// Round-3 changes vs round-0 (the 110.8us baseline):
//  - X staged at t-PAIR granularity with float4 (dwordx4) loads: thread loads 2x16B
//    from a channel pair covering a 100-float (2t x 50vm) window; halves the load
//    instruction count, doubles bytes/request and bytes-in-flight per issue window.
//    Pair loads issued after B0 of ODD iterations, converted after B1 of the SAME
//    iteration -- the exact register-hold distance round 0 proved safe at (256,3).
//    (Round 2 lesson: launch_bounds(256,4) made the allocator drop prefetch regs ->
//    x fetched twice from HBM; occupancy +33% bought only +5% BW. Stay at (256,3).)
//  - Xb is one 128-row buffer; halves indexed by tt&1 (== round-0 double buffer).
//    On odd iters the convert rewrites BOTH halves; all Xb reads (frags + residual)
//    complete before B1, so both halves are dead by then.
//  - Round-2-verified epilogue: stage-2 wave owns (o-half, w-half), computes BOTH m,
//    stores dense float2; residual read as ushort4 before B1.
#define N_  32
#define C_  64
#define T_  300
#define V_  25
#define M_  2
#define S_  3
#define O_  64
#define OS_ 192
#define TB  6             // t-values per block (even: pair staging needs even t0+tt+1 starts)
#define NT_BLK (T_/TB)    // 50
#define CTVM (C_*T_*V_*M_)   // 960000
#define TVM  (T_*V_*M_)      // 15000
#define VM   (V_*M_)         // 50
#define XPITCH 72         // shorts; 144B rows
#define YPITCH 72

typedef short  short8  __attribute__((ext_vector_type(8)));
typedef float  float4_ __attribute__((ext_vector_type(4)));
typedef unsigned short ushort4_ __attribute__((ext_vector_type(4)));

__device__ __forceinline__ short f2bf(float f) {   // fp32 -> bf16 RNE
    uint32_t u = __float_as_uint(f);
    u += 0x7FFFu + ((u >> 16) & 1u);
    return (short)(u >> 16);
}
__device__ __forceinline__ unsigned pk2bf(float a, float b) {  // lo=a, hi=b
    const uint32_t ua = (uint32_t)(uint16_t)f2bf(a);
    const uint32_t ub = (uint32_t)(uint16_t)f2bf(b);
    return ua | (ub << 16);
}
__device__ __forceinline__ float bf2f(unsigned short u) {
    return __uint_as_float(((unsigned)u) << 16);
}

// prep: W -> bf16 [os][c]; PA -> bf16 transposed+padded [s][w32][v32]; BN fold.
__global__ void stgcn_prep(const float* __restrict__ Wc, const float* __restrict__ PA,
                           const float* __restrict__ g,  const float* __restrict__ b,
                           const float* __restrict__ mn, const float* __restrict__ vr,
                           short* __restrict__ Wb, short* __restrict__ PAb,
                           float* __restrict__ scl, float* __restrict__ sft)
{
    const int i = blockIdx.x * 256 + threadIdx.x;
    if (i < OS_ * C_) Wb[i] = f2bf(Wc[i]);
    const int r = i - OS_ * C_;
    if (r >= 0 && r < S_ * 32 * 32) {
        const int s = r >> 10, rem = r & 1023, wp = rem >> 5, vp = rem & 31;
        const float val = (wp < V_ && vp < V_) ? PA[s * V_ * V_ + vp * V_ + wp] : 0.0f;
        PAb[r] = f2bf(val);
    }
    const int q = r - S_ * 32 * 32;
    if (q >= 0 && q < O_) {
        const float sc = g[q] * rsqrtf(vr[q] + 1e-5f);
        scl[q] = sc;
        sft[q] = b[q] - mn[q] * sc;
    }
}

__global__ __launch_bounds__(256, 3)
void stgcn_main(const float* __restrict__ x, const float* __restrict__ cb,
                const short* __restrict__ Wb, const short* __restrict__ PAb,
                const float* __restrict__ sclg, const float* __restrict__ sftg,
                float* __restrict__ out)
{
    __shared__ short Xb[128 * XPITCH];     // 18.4 KB: two t-halves (t-parity)
    __shared__ short Ys[OS_ * YPITCH];     // 27.6 KB
    __shared__ float sclS[O_], sftS[O_];

    const int tid  = threadIdx.x;
    const int wv   = tid >> 6;
    const int lane = tid & 63;
    const int quad = lane >> 4;
    const int l15  = lane & 15;

    const int n  = blockIdx.x / NT_BLK;
    const int t0 = (blockIdx.x % NT_BLK) * TB;
    const size_t xbase = (size_t)n * CTVM;

    // zero v-pad rows (25..31, 57..63) in BOTH halves, once
    for (int i = tid; i < 28 * XPITCH; i += 256) {
        const int pr = i / XPITCH, cc = i - pr * XPITCH;
        const int g  = pr / 7, w = pr - g * 7;
        const int pos = (g >> 1) * 64 + (g & 1) * 32 + 25 + w;
        Xb[pos * XPITCH + cc] = 0;
    }
    if (tid < O_) { sclS[tid] = sclg[tid]; sftS[tid] = sftg[tid]; }

    // ---- wave-constant fragments ----
    const int wbase = wv * 48;            // stage-1: this wave's 48 os rows
    short8 aW[3][2];                      // B-operand: B[k=c][n=os]
    #pragma unroll
    for (int mt = 0; mt < 3; ++mt)
        #pragma unroll
        for (int ks = 0; ks < 2; ++ks)
            aW[mt][ks] = *(const short8*)(Wb + (wbase + mt * 16 + l15) * C_ + ks * 32 + quad * 8);

    float cbw[3];                         // stage-1 bias: per COLUMN (os = l15-mapped)
    #pragma unroll
    for (int mt = 0; mt < 3; ++mt) cbw[mt] = cb[wbase + mt * 16 + l15];

    // stage-2: wave owns (o-half, w-half); computes BOTH m
    const int oh = wv >> 1, hh = wv & 1;
    const int wc = hh * 16 + l15;
    short8 bP[3];                         // B[k=v][n=w]
    #pragma unroll
    for (int s = 0; s < 3; ++s)
        bP[s] = *(const short8*)(PAb + s * 1024 + wc * 32 + quad * 8);

    // ---- prologue: stage pair (t0, t0+1) ----
    {
        const float* xp = x + xbase + (size_t)t0 * VM;
        #pragma unroll
        for (int k = 0; k < 4; ++k) {
            const int p = tid + (k << 8);          // 800 (cpair, q) slots
            if (p < 800) {
                const int cp = p / 25, q = p - cp * 25;
                const float4_ F0 = *(const float4_*)(xp + (size_t)(2 * cp)     * TVM + q * 4);
                const float4_ F1 = *(const float4_*)(xp + (size_t)(2 * cp + 1) * TVM + q * 4);
                #pragma unroll
                for (int j = 0; j < 4; ++j) {
                    const int f  = 4 * q + j;          // flat idx in 100-float window
                    const int dt = (f >= 50) ? 1 : 0;  // which t of the pair
                    const int r  = f - 50 * dt;
                    const int row = dt * 64 + (r & 1) * 32 + (r >> 1);  // half|m|v
                    ((unsigned*)Xb)[row * 36 + cp] = pk2bf(F0[j], F1[j]);
                }
            }
        }
    }

    for (int tt = 0; tt < TB; ++tt) {
        __syncthreads();   // B0: Xb half(tt) staged; Ys free for rewrite

        // ---- on odd iters: issue float4 pair-prefetch for (tt+1, tt+2) ----
        float4_ P0[4], P1[4];
        const bool pf = (tt & 1) && (tt + 1 < TB);
        if (pf) {
            const float* xp = x + xbase + (size_t)(t0 + tt + 1) * VM;  // even t start
            #pragma unroll
            for (int k = 0; k < 4; ++k) {
                const int p = tid + (k << 8);
                if (p < 800) {
                    const int cp = p / 25, q = p - cp * 25;
                    P0[k] = *(const float4_*)(xp + (size_t)(2 * cp)     * TVM + q * 4);
                    P1[k] = *(const float4_*)(xp + (size_t)(2 * cp + 1) * TVM + q * 4);
                }
            }
        }

        // ---- stage-1 A frags + residual (ALL Xb reads happen before B1) ----
        const short* Xc = Xb + (tt & 1) * (64 * XPITCH);
        short8 bX[4][2];                  // A[m=pos][k=c]
        #pragma unroll
        for (int nt = 0; nt < 4; ++nt)
            #pragma unroll
            for (int ks = 0; ks < 2; ++ks)
                bX[nt][ks] = *(const short8*)(Xc + (nt * 16 + l15) * XPITCH + ks * 32 + quad * 8);

        ushort4_ res[2][2];               // [otl][m] : residual bf16, 4 consecutive o
        #pragma unroll
        for (int otl = 0; otl < 2; ++otl)
            #pragma unroll
            for (int m = 0; m < 2; ++m)
                res[otl][m] = *(const ushort4_*)(Xc + (m * 32 + wc) * XPITCH + (oh * 2 + otl) * 16 + quad * 4);

        // ---- stage 1: D[pos][os] = X^T·W^T + cb ----
        #pragma unroll
        for (int mt = 0; mt < 3; ++mt) {
            #pragma unroll
            for (int nt = 0; nt < 4; ++nt) {
                float4_ acc = { cbw[mt], cbw[mt], cbw[mt], cbw[mt] };
                acc = __builtin_amdgcn_mfma_f32_16x16x32_bf16(bX[nt][0], aW[mt][0], acc, 0, 0, 0);
                acc = __builtin_amdgcn_mfma_f32_16x16x32_bf16(bX[nt][1], aW[mt][1], acc, 0, 0, 0);
                const int os = wbase + mt * 16 + l15;
                *(uint2*)(Ys + os * YPITCH + nt * 16 + quad * 4) =
                    make_uint2(pk2bf(acc[0], acc[1]), pk2bf(acc[2], acc[3]));
            }
        }
        __syncthreads();   // B1: Ys complete; Xb (both halves) fully consumed

        // ---- stage 2: Z[o][w] = sum_s Y_s[o][v] PA_s[v][w], both m per wave ----
        float4_ z[2][2];
        #pragma unroll
        for (int otl = 0; otl < 2; ++otl)
            #pragma unroll
            for (int m = 0; m < 2; ++m) { z[otl][m][0]=0.f; z[otl][m][1]=0.f; z[otl][m][2]=0.f; z[otl][m][3]=0.f; }
        #pragma unroll
        for (int s = 0; s < 3; ++s) {
            #pragma unroll
            for (int otl = 0; otl < 2; ++otl) {
                #pragma unroll
                for (int m = 0; m < 2; ++m) {
                    const short8 aY = *(const short8*)(Ys + (s * 64 + (oh * 2 + otl) * 16 + l15) * YPITCH + m * 32 + quad * 8);
                    z[otl][m] = __builtin_amdgcn_mfma_f32_16x16x32_bf16(aY, bP[s], z[otl][m], 0, 0, 0);
                }
            }
        }

        // ---- epilogue: BN + relu + residual + relu; dense float2 stores ----
        const int t = t0 + tt;
        if (wc < V_) {
            #pragma unroll
            for (int otl = 0; otl < 2; ++otl) {
                #pragma unroll
                for (int r = 0; r < 4; ++r) {
                    const int o = (oh * 2 + otl) * 16 + quad * 4 + r;
                    const float sc = sclS[o], sh = sftS[o];
                    float q0 = fmaf(z[otl][0][r], sc, sh);
                    q0 = fmaxf(q0, 0.0f);
                    q0 = fmaxf(q0 + bf2f((unsigned short)res[otl][0][r]), 0.0f);
                    float q1 = fmaf(z[otl][1][r], sc, sh);
                    q1 = fmaxf(q1, 0.0f);
                    q1 = fmaxf(q1 + bf2f((unsigned short)res[otl][1][r]), 0.0f);
                    *(float2*)(out + xbase + (size_t)o * TVM + (size_t)t * VM + wc * 2) =
                        make_float2(q0, q1);
                }
            }
        }

        // ---- convert prefetched pair into BOTH Xb halves (odd iters) ----
        if (pf) {
            #pragma unroll
            for (int k = 0; k < 4; ++k) {
                const int p = tid + (k << 8);
                if (p < 800) {
                    const int cp = p / 25, q = p - cp * 25;
                    #pragma unroll
                    for (int j = 0; j < 4; ++j) {
                        const int f  = 4 * q + j;
                        const int dt = (f >= 50) ? 1 : 0;
                        const int r  = f - 50 * dt;
                        const int row = dt * 64 + (r & 1) * 32 + (r >> 1);
                        ((unsigned*)Xb)[row * 36 + cp] = pk2bf(P0[k][j], P1[k][j]);
                    }
                }
            }
        }
    }
}

extern "C" void kernel_launch(void* const* d_in, const int* in_sizes, int n_in,
                              void* d_out, int out_size, void* d_ws, size_t ws_size,
                              hipStream_t stream)
{
    const float* x    = (const float*)d_in[0];  // (32,64,300,25,2)
    const float* PA   = (const float*)d_in[1];  // (3,25,25)
    const float* Wc   = (const float*)d_in[2];  // (192,64)
    const float* cb   = (const float*)d_in[3];  // (192,)
    const float* bn_g = (const float*)d_in[4];
    const float* bn_b = (const float*)d_in[5];
    const float* bn_m = (const float*)d_in[6];
    const float* bn_v = (const float*)d_in[7];
    float* out = (float*)d_out;

    char* ws = (char*)d_ws;
    short* Wb  = (short*)ws;                    // 12288 bf16
    short* PAb = (short*)(ws + 24576);          //  3072 bf16
    float* scl = (float*)(ws + 30720);          //    64 f32
    float* sft = (float*)(ws + 30976);          //    64 f32

    stgcn_prep<<<61, 256, 0, stream>>>(Wc, PA, bn_g, bn_b, bn_m, bn_v, Wb, PAb, scl, sft);
    stgcn_main<<<N_ * NT_BLK, 256, 0, stream>>>(x, cb, Wb, PAb, scl, sft, out);
}